// Round 1
// baseline (240.084 us; speedup 1.0000x reference)
//
#include <hip/hip_runtime.h>

#define N_NODES 50000
#define N_EDGES 300000
#define N_TOT   350000   // edges + self-loops
#define D       256
#define MPAD    50048    // N_NODES padded to multiple of 128 for GEMM
#define SCAN_B  196      // ceil(50000/256)

typedef __attribute__((ext_vector_type(8))) short bf16x8;
typedef __attribute__((ext_vector_type(4))) float f32x4;
typedef __attribute__((ext_vector_type(8))) unsigned short u16x8;
typedef __attribute__((ext_vector_type(4))) unsigned short u16x4;

__device__ __forceinline__ float bf2f(unsigned short b) {
    union { unsigned u; float f; } v; v.u = ((unsigned)b) << 16; return v.f;
}
__device__ __forceinline__ unsigned short f2bf(float f) {
    union { float f; unsigned u; } v; v.f = f;
    unsigned u = v.u;
    unsigned r = (u + 0x7FFFu + ((u >> 16) & 1u)) >> 16;   // round-nearest-even
    return (unsigned short)r;
}
__device__ __forceinline__ void g2lds16(const unsigned short* g, unsigned short* l) {
    __builtin_amdgcn_global_load_lds(
        (const __attribute__((address_space(1))) void*)g,
        (__attribute__((address_space(3))) void*)l, 16, 0, 0);
}

// ---- k1: hist + W-transpose + embed, all independent, grid = MPAD/8 = 6256 ----
__global__ __launch_bounds__(256) void k1_kernel(
        const float* __restrict__ x, const int* __restrict__ ei,
        const float* __restrict__ We, const float* __restrict__ be,
        const float* __restrict__ W1, const float* __restrict__ W2,
        int* __restrict__ cnt,
        unsigned short* __restrict__ Wt1, unsigned short* __restrict__ Wt2,
        unsigned short* __restrict__ hA) {
    int t = threadIdx.x, b = blockIdx.x;
    int tid = b * 256 + t;

    // histogram over dst (cnt pre-zeroed by memset)
    if (tid < N_TOT) {
        int dst = (tid < N_EDGES) ? ei[N_EDGES + tid] : (tid - N_EDGES);
        atomicAdd(&cnt[dst], 1);
    }
    // transpose + cast weights (first 512 blocks, 1 elem/thread)
    // orientation: consecutive tid -> consecutive tt -> COALESCED 2B writes;
    // strided 4B reads (stride 1KB) are absorbed by L2 (512KB working set).
    if (tid < 2 * D * D) {
        int wsel = tid >> 16, rem = tid & 65535;
        int bb = rem >> 8, tt = rem & 255;
        const float* W = wsel ? W2 : W1;
        unsigned short* Wt = wsel ? Wt2 : Wt1;
        Wt[bb * D + tt] = f2bf(W[tt * D + bb]);
    }
    // embed: block b -> nodes b*8 .. b*8+7 (pad rows get 0)
    float w[11];
    #pragma unroll
    for (int k = 0; k < 11; ++k) w[k] = We[k * D + t];
    float bb = be[t];
    #pragma unroll
    for (int ni = 0; ni < 8; ++ni) {
        int node = b * 8 + ni;
        float acc = 0.f;
        if (node < N_NODES) {
            acc = bb;
            #pragma unroll
            for (int k = 0; k < 11; ++k) acc += x[node * 11 + k] * w[k];
            acc = fmaxf(acc, 0.f);
        }
        hA[(size_t)node * D + t] = f2bf(acc);
    }
}

// ---- k3: rowptr materialization + CSR fill (packed src+norm, one 8B store) ----
__global__ __launch_bounds__(256) void k3_kernel(const int* __restrict__ ei,
                          const int* __restrict__ locs,
                          const int* __restrict__ bsum, const float* __restrict__ dis,
                          int* __restrict__ fc, int* __restrict__ rowptr,
                          int2* __restrict__ epk) {
    int tid = blockIdx.x * 256 + threadIdx.x;
    if (tid == 0) rowptr[0] = 0;
    if (tid < N_NODES)
        rowptr[tid + 1] = locs[tid] + bsum[tid >> 8];
    if (tid < N_TOT) {
        int src, dst;
        if (tid < N_EDGES) { src = ei[tid]; dst = ei[N_EDGES + tid]; }
        else               { src = dst = tid - N_EDGES; }
        int base = bsum[dst >> 8] + ((dst & 255) ? locs[dst - 1] : 0);
        int pos = base + atomicAdd(&fc[dst], 1);
        epk[pos] = make_int2(src, __float_as_int(dis[src] * dis[dst]));
    }
}

// ---- GEMM (m97-style) + optional k2 side-job in blocks (x<196, y==0) ----
// Epilogue uses SWAPPED-operand MFMA: mfma(b, a) transposes the C/D lane
// mapping so each lane holds 4 CONSECUTIVE columns per fragment -> one 8B
// store instead of four 2B stores (wave writes 16 rows x 32B contiguous).
__global__ __launch_bounds__(256) void gemm_kernel(const unsigned short* __restrict__ A,
                                                   const unsigned short* __restrict__ Bt,
                                                   unsigned short* __restrict__ C,
                                                   const int* __restrict__ cnt,
                                                   float* __restrict__ dis,
                                                   int* __restrict__ locs,
                                                   int* __restrict__ bsum,
                                                   int* __restrict__ done) {
    __shared__ unsigned short lA[128 * 32];
    __shared__ unsigned short lB[128 * 32];
    __shared__ int ws[4];
    __shared__ int amLast;
    int t = threadIdx.x;

    // ---- side job: k2 scan (only when cnt != nullptr) ----
    if (cnt && blockIdx.y == 0 && blockIdx.x < SCAN_B) {
        int lane = t & 63, wv4 = t >> 6;
        int i = blockIdx.x * 256 + t;
        int v = (i < N_NODES) ? cnt[i] : 0;
        if (i < N_NODES) dis[i] = rsqrtf((float)v);    // deg >= 1 (self-loop)
        int s = v;
        #pragma unroll
        for (int d = 1; d < 64; d <<= 1) {
            int u = __shfl_up(s, d, 64);
            if (lane >= d) s += u;
        }
        if (lane == 63) ws[wv4] = s;
        __syncthreads();
        int off = 0;
        #pragma unroll
        for (int k = 0; k < 4; ++k) if (k < wv4) off += ws[k];
        s += off;
        if (i < N_NODES) locs[i] = s;                  // inclusive local scan
        if (t == 255) {
            bsum[blockIdx.x] = s;
            __threadfence();
            amLast = (atomicAdd(done, 1) == SCAN_B - 1);
        }
        __syncthreads();
        if (amLast) {
            __threadfence();
            int vv = 0;
            if (t < SCAN_B)
                vv = __hip_atomic_load(&bsum[t], __ATOMIC_RELAXED, __HIP_MEMORY_SCOPE_AGENT);
            int ss = vv;
            #pragma unroll
            for (int d = 1; d < 64; d <<= 1) {
                int u = __shfl_up(ss, d, 64);
                if (lane >= d) ss += u;
            }
            __syncthreads();                           // ws reuse
            if (lane == 63) ws[wv4] = ss;
            __syncthreads();
            int off2 = 0;
            #pragma unroll
            for (int k = 0; k < 4; ++k) if (k < wv4) off2 += ws[k];
            ss += off2;
            if (t < SCAN_B) bsum[t] = ss - vv;         // exclusive block offsets
        }
        __syncthreads();
    }

    // ---- GEMM body ----
    int wv = t >> 6, lane = t & 63;
    int m0 = blockIdx.x * 128;
    int n0 = blockIdx.y * 128;
    int moff = (wv & 1) * 64, noff = (wv >> 1) * 64;
    int q = lane >> 4, r = lane & 15;

    int srow = t >> 2;
    int skof = (t & 3) * 8;

    const unsigned short* Ag0 = A  + (size_t)(m0 + srow) * D + skof;
    const unsigned short* Ag1 = Ag0 + (size_t)64 * D;
    const unsigned short* Bg0 = Bt + (size_t)(n0 + srow) * D + skof;
    const unsigned short* Bg1 = Bg0 + (size_t)64 * D;
    unsigned short* lA0 = lA + t * 8;
    unsigned short* lA1 = lA0 + 64 * 32;
    unsigned short* lB0 = lB + t * 8;
    unsigned short* lB1 = lB0 + 64 * 32;

    f32x4 acc[4][4] = {};
    for (int kk = 0; kk < D; kk += 32) {
        __syncthreads();
        g2lds16(Ag0 + kk, lA0);
        g2lds16(Ag1 + kk, lA1);
        g2lds16(Bg0 + kk, lB0);
        g2lds16(Bg1 + kk, lB1);
        __syncthreads();
        bf16x8 a[4], b[4];
        #pragma unroll
        for (int mt = 0; mt < 4; ++mt)
            a[mt] = *(const bf16x8*)(lA + (moff + mt * 16 + r) * 32 + q * 8);
        #pragma unroll
        for (int nt = 0; nt < 4; ++nt)
            b[nt] = *(const bf16x8*)(lB + (noff + nt * 16 + r) * 32 + q * 8);
        // swapped operands: first operand supplies the (q,reg) "row role",
        // so n gets (q,reg) and m gets (lane&15) -> transposed frag layout
        #pragma unroll
        for (int mt = 0; mt < 4; ++mt)
            #pragma unroll
            for (int nt = 0; nt < 4; ++nt)
                acc[mt][nt] = __builtin_amdgcn_mfma_f32_16x16x32_bf16(b[nt], a[mt], acc[mt][nt], 0, 0, 0);
    }
    #pragma unroll
    for (int mt = 0; mt < 4; ++mt) {
        int mrow = m0 + moff + mt * 16 + r;
        #pragma unroll
        for (int nt = 0; nt < 4; ++nt) {
            int ncol = n0 + noff + nt * 16 + (q << 2);
            u16x4 o;
            #pragma unroll
            for (int i = 0; i < 4; ++i) o[i] = f2bf(acc[mt][nt][i]);
            *(u16x4*)(C + (size_t)mrow * D + ncol) = o;
        }
    }
}

// ---- agg v7: wave per node, 8 edges/wave in flight (4 per half-wave).
// avg deg ~7 -> whole gather completes in ONE latency round; over-issued pad
// edges have nml=0 and src=0 (row 0 stays L2-hot), so no extra HBM traffic. ----
__global__ __launch_bounds__(256) void agg_kernel(const unsigned short* __restrict__ hw,
                                                  const int* __restrict__ rowptr,
                                                  const int2* __restrict__ epk,
                                                  const float* __restrict__ bias,
                                                  unsigned short* __restrict__ out_bf,
                                                  float* __restrict__ out_f32,
                                                  int mode) {
    int wid  = threadIdx.x >> 6;
    int lane = threadIdx.x & 63;
    int node = blockIdx.x * 4 + wid;
    if (node >= N_NODES) return;
    int s0 = rowptr[node], s1 = rowptr[node + 1];
    int half = lane >> 5, hl = lane & 31;

    float acc[8] = {};
    for (int base = s0; base < s1; base += 64) {   // one trip in practice (deg << 64)
        int ec = s1 - base; if (ec > 64) ec = 64;
        int srcl = 0; float nml = 0.f;
        if (lane < ec) {
            int2 ep = epk[base + lane];
            srcl = ep.x; nml = __int_as_float(ep.y);
        }
        int it = (ec + 1) >> 1;                    // #trips (2 edges each)
        for (int i = 0; i < it; i += 4) {          // chunk = 4 trips = 8 edges in flight
            int   e0 = (2 * i + half) & 63;
            int   e1 = (2 * i + 2 + half) & 63;
            int   e2 = (2 * i + 4 + half) & 63;
            int   e3 = (2 * i + 6 + half) & 63;
            int   sa = __shfl(srcl, e0, 64);
            float na = __shfl(nml,  e0, 64);
            int   sb = __shfl(srcl, e1, 64);
            float nb = __shfl(nml,  e1, 64);
            int   sc = __shfl(srcl, e2, 64);
            float nc = __shfl(nml,  e2, 64);
            int   sd = __shfl(srcl, e3, 64);
            float nd = __shfl(nml,  e3, 64);       // zero-norm past end of row
            u16x8 ha = *(const u16x8*)(hw + (size_t)sa * D + hl * 8);
            u16x8 hb = *(const u16x8*)(hw + (size_t)sb * D + hl * 8);
            u16x8 hc = *(const u16x8*)(hw + (size_t)sc * D + hl * 8);
            u16x8 hd = *(const u16x8*)(hw + (size_t)sd * D + hl * 8);
            #pragma unroll
            for (int k = 0; k < 8; ++k) acc[k] += na * bf2f(ha[k]);
            #pragma unroll
            for (int k = 0; k < 8; ++k) acc[k] += nb * bf2f(hb[k]);
            #pragma unroll
            for (int k = 0; k < 8; ++k) acc[k] += nc * bf2f(hc[k]);
            #pragma unroll
            for (int k = 0; k < 8; ++k) acc[k] += nd * bf2f(hd[k]);
        }
    }
    #pragma unroll
    for (int k = 0; k < 8; ++k) acc[k] += __shfl_xor(acc[k], 32, 64);

    if (lane < 32) {
        int c = hl * 8;
        float4 bv0 = *(const float4*)(bias + c);
        float4 bv1 = *(const float4*)(bias + c + 4);
        float v[8];
        v[0] = acc[0] + bv0.x; v[1] = acc[1] + bv0.y;
        v[2] = acc[2] + bv0.z; v[3] = acc[3] + bv0.w;
        v[4] = acc[4] + bv1.x; v[5] = acc[5] + bv1.y;
        v[6] = acc[6] + bv1.z; v[7] = acc[7] + bv1.w;
        if (mode) {
            u16x8 ov;
            #pragma unroll
            for (int k = 0; k < 8; ++k) ov[k] = f2bf(fmaxf(v[k], 0.f));
            *(u16x8*)(out_bf + (size_t)node * D + c) = ov;
        } else {
            float4 o0 = { v[0], v[1], v[2], v[3] };
            float4 o1 = { v[4], v[5], v[6], v[7] };
            *(float4*)(out_f32 + (size_t)node * D + c)     = o0;
            *(float4*)(out_f32 + (size_t)node * D + c + 4) = o1;
        }
    }
}

extern "C" void kernel_launch(void* const* d_in, const int* in_sizes, int n_in,
                              void* d_out, int out_size, void* d_ws, size_t ws_size,
                              hipStream_t stream) {
    const float* x  = (const float*)d_in[0];
    const int*   ei = (const int*)d_in[1];
    const float* We = (const float*)d_in[2];
    const float* be = (const float*)d_in[3];
    const float* W1 = (const float*)d_in[4];
    const float* b1 = (const float*)d_in[5];
    const float* W2 = (const float*)d_in[6];
    const float* b2 = (const float*)d_in[7];
    float* out = (float*)d_out;

    char* w = (char*)d_ws;
    auto alloc = [&](size_t bytes) {
        char* p = w;
        w += (bytes + 255) & ~(size_t)255;
        return p;
    };
    // cnt, fc, done contiguous -> single memset covers all three
    int*            cnt    = (int*)alloc((size_t)N_NODES * 4);
    int*            fc     = (int*)alloc((size_t)N_NODES * 4);
    int*            done   = (int*)alloc(4);
    size_t zero_span = (size_t)((char*)(done + 64) - (char*)cnt);
    int*            rowptr = (int*)alloc((size_t)(N_NODES + 1) * 4);
    int*            locs   = (int*)alloc((size_t)N_NODES * 4);
    int*            bsum   = (int*)alloc((size_t)SCAN_B * 4);
    float*          dis    = (float*)alloc((size_t)N_NODES * 4);
    int2*           epk    = (int2*)alloc((size_t)N_TOT * 8);
    unsigned short* Wt1    = (unsigned short*)alloc((size_t)D * D * 2);
    unsigned short* Wt2    = (unsigned short*)alloc((size_t)D * D * 2);
    unsigned short* hA     = (unsigned short*)alloc((size_t)MPAD * D * 2);
    unsigned short* hW     = (unsigned short*)alloc((size_t)MPAD * D * 2);

    hipMemsetAsync(cnt, 0, zero_span, stream);
    k1_kernel<<<MPAD / 8, 256, 0, stream>>>(x, ei, We, be, W1, W2, cnt, Wt1, Wt2, hA);

    dim3 ggrid(MPAD / 128, 2);
    // gemm1 carries the k2 scan side-job (needs only k1's cnt)
    gemm_kernel<<<ggrid, 256, 0, stream>>>(hA, Wt1, hW, cnt, dis, locs, bsum, done);
    k3_kernel<<<(N_TOT + 255) / 256, 256, 0, stream>>>(ei, locs, bsum, dis, fc,
                                                       rowptr, epk);
    agg_kernel<<<(N_NODES + 3) / 4, 256, 0, stream>>>(hW, rowptr, epk, b1,
                                                      hA, nullptr, 1);

    gemm_kernel<<<ggrid, 256, 0, stream>>>(hA, Wt2, hW, nullptr, nullptr, nullptr,
                                           nullptr, nullptr);
    agg_kernel<<<(N_NODES + 3) / 4, 256, 0, stream>>>(hW, rowptr, epk, b2,
                                                      nullptr, out, 0);
}

// Round 2
// 231.455 us; speedup vs baseline: 1.0373x; 1.0373x over previous
//
#include <hip/hip_runtime.h>

#define N_NODES 50000
#define N_EDGES 300000
#define N_TOT   350000   // edges + self-loops
#define D       256
#define MPAD    50048    // N_NODES padded to multiple of 128 for GEMM
#define SCAN_B  196      // ceil(50000/256)
#define GEMM_B  784      // 8 XCDs x 98 slots (covers 391 M-tiles x 2 N-halves)

typedef __attribute__((ext_vector_type(8))) short bf16x8;
typedef __attribute__((ext_vector_type(4))) float f32x4;
typedef __attribute__((ext_vector_type(8))) unsigned short u16x8;
typedef __attribute__((ext_vector_type(4))) unsigned short u16x4;

__device__ __forceinline__ float bf2f(unsigned short b) {
    union { unsigned u; float f; } v; v.u = ((unsigned)b) << 16; return v.f;
}
__device__ __forceinline__ unsigned short f2bf(float f) {
    union { float f; unsigned u; } v; v.f = f;
    unsigned u = v.u;
    unsigned r = (u + 0x7FFFu + ((u >> 16) & 1u)) >> 16;   // round-nearest-even
    return (unsigned short)r;
}
__device__ __forceinline__ void g2lds16(const unsigned short* g, unsigned short* l) {
    __builtin_amdgcn_global_load_lds(
        (const __attribute__((address_space(1))) void*)g,
        (__attribute__((address_space(3))) void*)l, 16, 0, 0);
}

// ---- k1: hist + W-transpose + embed, all independent, grid = MPAD/8 = 6256 ----
__global__ __launch_bounds__(256) void k1_kernel(
        const float* __restrict__ x, const int* __restrict__ ei,
        const float* __restrict__ We, const float* __restrict__ be,
        const float* __restrict__ W1, const float* __restrict__ W2,
        int* __restrict__ cnt,
        unsigned short* __restrict__ Wt1, unsigned short* __restrict__ Wt2,
        unsigned short* __restrict__ hA) {
    int t = threadIdx.x, b = blockIdx.x;
    int tid = b * 256 + t;

    // histogram over dst (cnt pre-zeroed by memset)
    if (tid < N_TOT) {
        int dst = (tid < N_EDGES) ? ei[N_EDGES + tid] : (tid - N_EDGES);
        atomicAdd(&cnt[dst], 1);
    }
    // transpose + cast weights (first 512 blocks, 1 elem/thread)
    // round-0 orientation: consecutive tid -> consecutive bb -> coalesced READS
    if (tid < 2 * D * D) {
        int wsel = tid >> 16, rem = tid & 65535;
        int tt = rem >> 8, bb = rem & 255;
        const float* W = wsel ? W2 : W1;
        unsigned short* Wt = wsel ? Wt2 : Wt1;
        Wt[bb * D + tt] = f2bf(W[tt * D + bb]);
    }
    // embed: block b -> nodes b*8 .. b*8+7 (pad rows get 0)
    float w[11];
    #pragma unroll
    for (int k = 0; k < 11; ++k) w[k] = We[k * D + t];
    float bb = be[t];
    #pragma unroll
    for (int ni = 0; ni < 8; ++ni) {
        int node = b * 8 + ni;
        float acc = 0.f;
        if (node < N_NODES) {
            acc = bb;
            #pragma unroll
            for (int k = 0; k < 11; ++k) acc += x[node * 11 + k] * w[k];
            acc = fmaxf(acc, 0.f);
        }
        hA[(size_t)node * D + t] = f2bf(acc);
    }
}

// ---- k3: rowptr materialization + CSR fill (packed src+norm, one 8B store) ----
__global__ __launch_bounds__(256) void k3_kernel(const int* __restrict__ ei,
                          const int* __restrict__ locs,
                          const int* __restrict__ bsum, const float* __restrict__ dis,
                          int* __restrict__ fc, int* __restrict__ rowptr,
                          int2* __restrict__ epk) {
    int tid = blockIdx.x * 256 + threadIdx.x;
    if (tid == 0) rowptr[0] = 0;
    if (tid < N_NODES)
        rowptr[tid + 1] = locs[tid] + bsum[tid >> 8];
    if (tid < N_TOT) {
        int src, dst;
        if (tid < N_EDGES) { src = ei[tid]; dst = ei[N_EDGES + tid]; }
        else               { src = dst = tid - N_EDGES; }
        int base = bsum[dst >> 8] + ((dst & 255) ? locs[dst - 1] : 0);
        int pos = base + atomicAdd(&fc[dst], 1);
        epk[pos] = make_int2(src, __float_as_int(dis[src] * dis[dst]));
    }
}

// ---- GEMM v3: BK=64 (8 barriers not 16), 1-D grid with chunked XCD mapping
// co-locating the (m, y=0)/(m, y=1) pair on one XCD so the A-panel is fetched
// from HBM once and hits XCD-L2 the second time. LDS [128][64] rows would put
// all reads in 4 bank-groups, so chunks are XOR-swizzled c' = c ^ (row&7) with
// the inverse swizzle applied to the GLOBAL source (rule: both-sides-or-neither
// with global_load_lds). Swapped-operand MFMA epilogue (8B stores). ----
__global__ __launch_bounds__(256) void gemm_kernel(const unsigned short* __restrict__ A,
                                                   const unsigned short* __restrict__ Bt,
                                                   unsigned short* __restrict__ C,
                                                   const int* __restrict__ cnt,
                                                   float* __restrict__ dis,
                                                   int* __restrict__ locs,
                                                   int* __restrict__ bsum,
                                                   int* __restrict__ done) {
    __shared__ unsigned short lA[128 * 64];   // 16KB
    __shared__ unsigned short lB[128 * 64];   // 16KB
    __shared__ int ws[4];
    __shared__ int amLast;
    int t = threadIdx.x;
    int bid = blockIdx.x;

    // chunked pair mapping: xcd = bid%8 (HW round-robin assumption; perf-only)
    int xcd = bid & 7, s = bid >> 3;
    int pair = xcd * 49 + (s >> 1);           // M-tile
    int ny   = s & 1;                         // N-half
    if (pair >= MPAD / 128) return;           // bids 775/783 only; never scan blocks

    // ---- side job: k2 scan (only when cnt != nullptr), blocks bid<196 ----
    if (cnt && bid < SCAN_B) {
        int lane = t & 63, wv4 = t >> 6;
        int i = bid * 256 + t;
        int v = (i < N_NODES) ? cnt[i] : 0;
        if (i < N_NODES) dis[i] = rsqrtf((float)v);    // deg >= 1 (self-loop)
        int ssum = v;
        #pragma unroll
        for (int d = 1; d < 64; d <<= 1) {
            int u = __shfl_up(ssum, d, 64);
            if (lane >= d) ssum += u;
        }
        if (lane == 63) ws[wv4] = ssum;
        __syncthreads();
        int off = 0;
        #pragma unroll
        for (int k = 0; k < 4; ++k) if (k < wv4) off += ws[k];
        ssum += off;
        if (i < N_NODES) locs[i] = ssum;               // inclusive local scan
        if (t == 255) {
            bsum[bid] = ssum;
            __threadfence();
            amLast = (atomicAdd(done, 1) == SCAN_B - 1);
        }
        __syncthreads();
        if (amLast) {
            __threadfence();
            int vv = 0;
            if (t < SCAN_B)
                vv = __hip_atomic_load(&bsum[t], __ATOMIC_RELAXED, __HIP_MEMORY_SCOPE_AGENT);
        int ss = vv;
            #pragma unroll
            for (int d = 1; d < 64; d <<= 1) {
                int u = __shfl_up(ss, d, 64);
                if (lane >= d) ss += u;
            }
            __syncthreads();                           // ws reuse
            if (lane == 63) ws[wv4] = ss;
            __syncthreads();
            int off2 = 0;
            #pragma unroll
            for (int k = 0; k < 4; ++k) if (k < wv4) off2 += ws[k];
            ss += off2;
            if (t < SCAN_B) bsum[t] = ss - vv;         // exclusive block offsets
        }
        __syncthreads();
    }

    // ---- GEMM body ----
    int wv = t >> 6, lane = t & 63;
    int m0 = pair * 128;
    int n0 = ny * 128;
    int moff = (wv & 1) * 64, noff = (wv >> 1) * 64;
    int q = lane >> 4, r = lane & 15;

    // staging: 4 chunks/thread/tile; idx = j*256+t -> row=idx>>3, slot=idx&7,
    // source chunk c = slot ^ (row&7)
    int srow[4], scol[4];
    #pragma unroll
    for (int j = 0; j < 4; ++j) {
        int idx = j * 256 + t;
        srow[j] = idx >> 3;
        scol[j] = ((idx & 7) ^ (srow[j] & 7)) * 8;
    }

    f32x4 acc[4][4] = {};
    for (int kk = 0; kk < D; kk += 64) {
        __syncthreads();
        #pragma unroll
        for (int j = 0; j < 4; ++j) {
            int idx = j * 256 + t;
            g2lds16(A  + (size_t)(m0 + srow[j]) * D + kk + scol[j], lA + idx * 8);
            g2lds16(Bt + (size_t)(n0 + srow[j]) * D + kk + scol[j], lB + idx * 8);
        }
        __syncthreads();
        #pragma unroll
        for (int ks = 0; ks < 2; ++ks) {
            bf16x8 a[4], b[4];
            #pragma unroll
            for (int mt = 0; mt < 4; ++mt) {
                int row = moff + mt * 16 + r;
                a[mt] = *(const bf16x8*)(lA + row * 64 + (((ks * 4 + q) ^ (r & 7)) * 8));
            }
            #pragma unroll
            for (int nt = 0; nt < 4; ++nt) {
                int row = noff + nt * 16 + r;
                b[nt] = *(const bf16x8*)(lB + row * 64 + (((ks * 4 + q) ^ (r & 7)) * 8));
            }
            #pragma unroll
            for (int mt = 0; mt < 4; ++mt)
                #pragma unroll
                for (int nt = 0; nt < 4; ++nt)
                    acc[mt][nt] = __builtin_amdgcn_mfma_f32_16x16x32_bf16(b[nt], a[mt], acc[mt][nt], 0, 0, 0);
        }
    }
    #pragma unroll
    for (int mt = 0; mt < 4; ++mt) {
        int mrow = m0 + moff + mt * 16 + r;
        #pragma unroll
        for (int nt = 0; nt < 4; ++nt) {
            int ncol = n0 + noff + nt * 16 + (q << 2);
            u16x4 o;
            #pragma unroll
            for (int i = 0; i < 4; ++i) o[i] = f2bf(acc[mt][nt][i]);
            *(u16x4*)(C + (size_t)mrow * D + ncol) = o;
        }
    }
}

// ---- agg v7: wave per node, 8 edges/wave in flight (4 per half-wave).
// avg deg ~7 -> whole gather completes in ONE latency round; over-issued pad
// edges have nml=0 and src=0 (row 0 stays L1-hot), so no extra HBM traffic. ----
__global__ __launch_bounds__(256) void agg_kernel(const unsigned short* __restrict__ hw,
                                                  const int* __restrict__ rowptr,
                                                  const int2* __restrict__ epk,
                                                  const float* __restrict__ bias,
                                                  unsigned short* __restrict__ out_bf,
                                                  float* __restrict__ out_f32,
                                                  int mode) {
    int wid  = threadIdx.x >> 6;
    int lane = threadIdx.x & 63;
    int node = blockIdx.x * 4 + wid;
    if (node >= N_NODES) return;
    int s0 = rowptr[node], s1 = rowptr[node + 1];
    int half = lane >> 5, hl = lane & 31;

    float acc[8] = {};
    for (int base = s0; base < s1; base += 64) {   // one trip in practice (deg << 64)
        int ec = s1 - base; if (ec > 64) ec = 64;
        int srcl = 0; float nml = 0.f;
        if (lane < ec) {
            int2 ep = epk[base + lane];
            srcl = ep.x; nml = __int_as_float(ep.y);
        }
        int it = (ec + 1) >> 1;                    // #trips (2 edges each)
        for (int i = 0; i < it; i += 4) {          // chunk = 4 trips = 8 edges in flight
            int   e0 = (2 * i + half) & 63;
            int   e1 = (2 * i + 2 + half) & 63;
            int   e2 = (2 * i + 4 + half) & 63;
            int   e3 = (2 * i + 6 + half) & 63;
            int   sa = __shfl(srcl, e0, 64);
            float na = __shfl(nml,  e0, 64);
            int   sb = __shfl(srcl, e1, 64);
            float nb = __shfl(nml,  e1, 64);
            int   sc = __shfl(srcl, e2, 64);
            float nc = __shfl(nml,  e2, 64);
            int   sd = __shfl(srcl, e3, 64);
            float nd = __shfl(nml,  e3, 64);       // zero-norm past end of row
            u16x8 ha = *(const u16x8*)(hw + (size_t)sa * D + hl * 8);
            u16x8 hb = *(const u16x8*)(hw + (size_t)sb * D + hl * 8);
            u16x8 hc = *(const u16x8*)(hw + (size_t)sc * D + hl * 8);
            u16x8 hd = *(const u16x8*)(hw + (size_t)sd * D + hl * 8);
            #pragma unroll
            for (int k = 0; k < 8; ++k) acc[k] += na * bf2f(ha[k]);
            #pragma unroll
            for (int k = 0; k < 8; ++k) acc[k] += nb * bf2f(hb[k]);
            #pragma unroll
            for (int k = 0; k < 8; ++k) acc[k] += nc * bf2f(hc[k]);
            #pragma unroll
            for (int k = 0; k < 8; ++k) acc[k] += nd * bf2f(hd[k]);
        }
    }
    #pragma unroll
    for (int k = 0; k < 8; ++k) acc[k] += __shfl_xor(acc[k], 32, 64);

    if (lane < 32) {
        int c = hl * 8;
        float4 bv0 = *(const float4*)(bias + c);
        float4 bv1 = *(const float4*)(bias + c + 4);
        float v[8];
        v[0] = acc[0] + bv0.x; v[1] = acc[1] + bv0.y;
        v[2] = acc[2] + bv0.z; v[3] = acc[3] + bv0.w;
        v[4] = acc[4] + bv1.x; v[5] = acc[5] + bv1.y;
        v[6] = acc[6] + bv1.z; v[7] = acc[7] + bv1.w;
        if (mode) {
            u16x8 ov;
            #pragma unroll
            for (int k = 0; k < 8; ++k) ov[k] = f2bf(fmaxf(v[k], 0.f));
            *(u16x8*)(out_bf + (size_t)node * D + c) = ov;
        } else {
            float4 o0 = { v[0], v[1], v[2], v[3] };
            float4 o1 = { v[4], v[5], v[6], v[7] };
            *(float4*)(out_f32 + (size_t)node * D + c)     = o0;
            *(float4*)(out_f32 + (size_t)node * D + c + 4) = o1;
        }
    }
}

extern "C" void kernel_launch(void* const* d_in, const int* in_sizes, int n_in,
                              void* d_out, int out_size, void* d_ws, size_t ws_size,
                              hipStream_t stream) {
    const float* x  = (const float*)d_in[0];
    const int*   ei = (const int*)d_in[1];
    const float* We = (const float*)d_in[2];
    const float* be = (const float*)d_in[3];
    const float* W1 = (const float*)d_in[4];
    const float* b1 = (const float*)d_in[5];
    const float* W2 = (const float*)d_in[6];
    const float* b2 = (const float*)d_in[7];
    float* out = (float*)d_out;

    char* w = (char*)d_ws;
    auto alloc = [&](size_t bytes) {
        char* p = w;
        w += (bytes + 255) & ~(size_t)255;
        return p;
    };
    // cnt, fc, done contiguous -> single memset covers all three
    int*            cnt    = (int*)alloc((size_t)N_NODES * 4);
    int*            fc     = (int*)alloc((size_t)N_NODES * 4);
    int*            done   = (int*)alloc(4);
    size_t zero_span = (size_t)((char*)(done + 64) - (char*)cnt);
    int*            rowptr = (int*)alloc((size_t)(N_NODES + 1) * 4);
    int*            locs   = (int*)alloc((size_t)N_NODES * 4);
    int*            bsum   = (int*)alloc((size_t)SCAN_B * 4);
    float*          dis    = (float*)alloc((size_t)N_NODES * 4);
    int2*           epk    = (int2*)alloc((size_t)N_TOT * 8);
    unsigned short* Wt1    = (unsigned short*)alloc((size_t)D * D * 2);
    unsigned short* Wt2    = (unsigned short*)alloc((size_t)D * D * 2);
    unsigned short* hA     = (unsigned short*)alloc((size_t)MPAD * D * 2);
    unsigned short* hW     = (unsigned short*)alloc((size_t)MPAD * D * 2);

    hipMemsetAsync(cnt, 0, zero_span, stream);
    k1_kernel<<<MPAD / 8, 256, 0, stream>>>(x, ei, We, be, W1, W2, cnt, Wt1, Wt2, hA);

    // gemm1 carries the k2 scan side-job (needs only k1's cnt)
    gemm_kernel<<<GEMM_B, 256, 0, stream>>>(hA, Wt1, hW, cnt, dis, locs, bsum, done);
    k3_kernel<<<(N_TOT + 255) / 256, 256, 0, stream>>>(ei, locs, bsum, dis, fc,
                                                       rowptr, epk);
    agg_kernel<<<(N_NODES + 3) / 4, 256, 0, stream>>>(hW, rowptr, epk, b1,
                                                      hA, nullptr, 1);

    gemm_kernel<<<GEMM_B, 256, 0, stream>>>(hA, Wt2, hW, nullptr, nullptr, nullptr,
                                            nullptr, nullptr);
    agg_kernel<<<(N_NODES + 3) / 4, 256, 0, stream>>>(hW, rowptr, epk, b2,
                                                      nullptr, out, 0);
}